// Round 10
// baseline (288.792 us; speedup 1.0000x reference)
//
#include <hip/hip_runtime.h>
#include <hip/hip_bf16.h>
#include <cstdint>
#include <cstddef>

#define BT    16384   // B*T
#define DIN   4096
#define DOUT  4096
#define RR    64
#define TSEQ  2048
#define NADP  8

typedef float  f32x4  __attribute__((ext_vector_type(4)));
typedef __bf16 bf16x8 __attribute__((ext_vector_type(8)));

static __device__ __forceinline__ unsigned short bf16_bits(float f) {
    return __builtin_bit_cast(unsigned short, (__bf16)f);
}

// inter2 swizzled layout: [mblk(1024)][rb(8)][mrow(16)][j(8)]
// holds inter[mblk*16+mrow][rb*8+j]
static __device__ __forceinline__ size_t i2_idx(int mblk, int rb, int mrow, int j) {
    return ((((size_t)mblk * 8 + rb) * 16 + mrow) * 8 + j);
}

// ---------------------------------------------------------------------------
// k_prep_a: At2[a][kb][r][j] = bf16(A[a][kb*8+j][r]).  (R8 verbatim, passed)
// ---------------------------------------------------------------------------
__global__ __launch_bounds__(256) void k_prep_a(
    const float* __restrict__ A, __bf16* __restrict__ At2)
{
    const int gtid = blockIdx.x * 256 + threadIdx.x;
    const int r  = gtid & 63;
    const int kb = (gtid >> 6) & (DIN / 8 - 1);
    const int a  = gtid >> 15;
    const float* __restrict__ src = A + (size_t)a * DIN * RR + (size_t)kb * 8 * RR + r;
    unsigned int u[4];
    #pragma unroll
    for (int p = 0; p < 4; ++p) {
        unsigned int lo = bf16_bits(src[(2 * p + 0) * RR]);
        unsigned int hi = bf16_bits(src[(2 * p + 1) * RR]);
        u[p] = lo | (hi << 16);
    }
    *(uint4*)&At2[(size_t)gtid * 8] = make_uint4(u[0], u[1], u[2], u[3]);
}

// ---------------------------------------------------------------------------
// k_prep_b: Bp[a][rb][o][j] = bf16(B[a][rb*8+j][o]).  (R8 verbatim, passed)
// ---------------------------------------------------------------------------
__global__ __launch_bounds__(256) void k_prep_b(
    const float* __restrict__ Bw, __bf16* __restrict__ Bp)
{
    const int gtid = blockIdx.x * 256 + threadIdx.x;
    const int o  = gtid & (DOUT - 1);
    const int rb = (gtid >> 12) & 7;
    const int a  = gtid >> 15;
    const float* __restrict__ src = Bw + (size_t)a * RR * DOUT + (size_t)rb * 8 * DOUT + o;
    unsigned int u[4];
    #pragma unroll
    for (int p = 0; p < 4; ++p) {
        unsigned int lo = bf16_bits(src[(2 * p + 0) * DOUT]);
        unsigned int hi = bf16_bits(src[(2 * p + 1) * DOUT]);
        u[p] = lo | (hi << 16);
    }
    *(uint4*)&Bp[(size_t)gtid * 8] = make_uint4(u[0], u[1], u[2], u[3]);
}

// ---------------------------------------------------------------------------
// k_xa: inter2 <- bf16( x @ A[a] ).
// grid BT/16 = 1024 blocks (16 m-rows), 4 waves -> 4 waves/SIMD TLP.
// Wave rw owns r-tile [rw*16,+16). Within the wave, K is split into 4
// segments, each an independent MFMA chain (ILP=4); chains merge with a
// pure in-register add (no cross-lane, no LDS). Fragments: one 16B
// coalesced load each (At2 layout).
// ---------------------------------------------------------------------------
__global__ __launch_bounds__(256, 1) void k_xa(
    const float* __restrict__ x, const int* __restrict__ idx,
    const __bf16* __restrict__ At2, __bf16* __restrict__ inter2)
{
    const int m0   = blockIdx.x * 16;
    const int a    = idx[m0 / TSEQ];
    const int rw   = threadIdx.x >> 6, lane = threadIdx.x & 63;
    const int mr   = lane & 15, kg = lane >> 4;
    const int rcol = rw * 16 + mr;
    const float*  __restrict__ xrow = x   + (size_t)(m0 + mr) * DIN + kg * 8;
    const __bf16* __restrict__ Aw   = At2 + (size_t)a * RR * DIN;

    f32x4 z = {0.f, 0.f, 0.f, 0.f};
    f32x4 acc[4] = {z, z, z, z};   // one chain per K-segment of 1024

    #pragma unroll 2
    for (int ks = 0; ks < 32; ++ks) {
        #pragma unroll
        for (int c = 0; c < 4; ++c) {
            const int koff = c * 1024 + ks * 32;        // + kg*8 in xrow base
            float4 u0 = *(const float4*)(xrow + koff);
            float4 u1 = *(const float4*)(xrow + koff + 4);
            bf16x8 af;
            af[0] = (__bf16)u0.x; af[1] = (__bf16)u0.y;
            af[2] = (__bf16)u0.z; af[3] = (__bf16)u0.w;
            af[4] = (__bf16)u1.x; af[5] = (__bf16)u1.y;
            af[6] = (__bf16)u1.z; af[7] = (__bf16)u1.w;
            // B-operand: k = c*1024 + ks*32 + kg*8 .. +7, r = rcol
            bf16x8 bf = *(const bf16x8*)
                &Aw[((size_t)(c * 128 + ks * 4 + kg) * 64 + rcol) * 8];
            acc[c] = __builtin_amdgcn_mfma_f32_16x16x32_bf16(af, bf, acc[c], 0, 0, 0);
        }
    }

    f32x4 sum = acc[0] + acc[1] + acc[2] + acc[3];

    // D layout (R3-verified): row = kg*4+q (m), col = mr -> r = rcol
    const int rb = rw * 2 + (mr >> 3), j = mr & 7;
    #pragma unroll
    for (int q = 0; q < 4; ++q)
        inter2[i2_idx(blockIdx.x, rb, kg * 4 + q, j)] = (__bf16)sum[q];
}

// ---------------------------------------------------------------------------
// k_by: out = base + s * (inter @ B).  (R8/R9 verbatim, ~6.5 TB/s)
// ---------------------------------------------------------------------------
__global__ __launch_bounds__(256) void k_by(
    const __bf16* __restrict__ inter2, const float* __restrict__ base,
    const int* __restrict__ idx, const __bf16* __restrict__ Bp,
    const float* __restrict__ scal, float* __restrict__ out)
{
    const int o0 = blockIdx.x * 64;
    const int m0 = blockIdx.y * 64;
    const int a  = idx[m0 / TSEQ];
    const float s = scal[a];
    const __bf16* __restrict__ Ba = Bp + (size_t)a * RR * DOUT;
    const int lane = threadIdx.x & 63;
    const int w    = threadIdx.x >> 6;
    const int mr   = lane & 15, kg = lane >> 4;
    const int oc   = o0 + w * 16 + mr;

    f32x4 z = {0.f, 0.f, 0.f, 0.f};
    f32x4 acc[4] = {z, z, z, z};

    #pragma unroll
    for (int ksub = 0; ksub < 2; ++ksub) {
        const int rb = ksub * 4 + kg;
        bf16x8 bfA = *(const bf16x8*)&Ba[((size_t)rb * DOUT + oc) * 8];
        #pragma unroll
        for (int mt = 0; mt < 4; ++mt) {
            bf16x8 afB = *(const bf16x8*)&inter2[i2_idx(m0 / 16 + mt, rb, mr, 0)];
            acc[mt] = __builtin_amdgcn_mfma_f32_16x16x32_bf16(bfA, afB, acc[mt], 0, 0, 0);
        }
    }

    #pragma unroll
    for (int mt = 0; mt < 4; ++mt) {
        size_t off = (size_t)(m0 + mt * 16 + mr) * DOUT + o0 + w * 16 + kg * 4;
        float4 bv = *(const float4*)&base[off];
        float4 o;
        o.x = bv.x + s * acc[mt][0];
        o.y = bv.y + s * acc[mt][1];
        o.z = bv.z + s * acc[mt][2];
        o.w = bv.w + s * acc[mt][3];
        *(float4*)&out[off] = o;
    }
}

// ---------------------------------------------------------------------------
// Fallback kernels (R6 verbatim, 2 MB ws) if ws_size < 10 MB.
// ---------------------------------------------------------------------------
__global__ __launch_bounds__(256) void k_xa_fb(
    const float* __restrict__ x, const int* __restrict__ idx,
    const float* __restrict__ A, __bf16* __restrict__ inter)
{
    const int m0   = blockIdx.x * 32;
    const int a    = idx[m0 / TSEQ];
    const float* __restrict__ Aa = A + (size_t)a * DIN * RR;
    const int lane = threadIdx.x & 63;
    const int rw   = threadIdx.x >> 6;
    const int mr   = lane & 15, kg = lane >> 4;
    const int rcol = rw * 16 + mr;
    const float* __restrict__ xrow0 = x + (size_t)(m0 + mr) * DIN;
    const float* __restrict__ xrow1 = x + (size_t)(m0 + 16 + mr) * DIN;

    f32x4 acc0 = {0.f, 0.f, 0.f, 0.f};
    f32x4 acc1 = {0.f, 0.f, 0.f, 0.f};

    for (int k0 = 0; k0 < DIN; k0 += 64) {
        #pragma unroll
        for (int ksub = 0; ksub < 2; ++ksub) {
            const int koff = k0 + ksub * 32 + kg * 8;
            float4 u0 = *(const float4*)&xrow0[koff];
            float4 u1 = *(const float4*)&xrow0[koff + 4];
            float4 v0 = *(const float4*)&xrow1[koff];
            float4 v1 = *(const float4*)&xrow1[koff + 4];
            bf16x8 af0, af1;
            af0[0] = (__bf16)u0.x; af0[1] = (__bf16)u0.y;
            af0[2] = (__bf16)u0.z; af0[3] = (__bf16)u0.w;
            af0[4] = (__bf16)u1.x; af0[5] = (__bf16)u1.y;
            af0[6] = (__bf16)u1.z; af0[7] = (__bf16)u1.w;
            af1[0] = (__bf16)v0.x; af1[1] = (__bf16)v0.y;
            af1[2] = (__bf16)v0.z; af1[3] = (__bf16)v0.w;
            af1[4] = (__bf16)v1.x; af1[5] = (__bf16)v1.y;
            af1[6] = (__bf16)v1.z; af1[7] = (__bf16)v1.w;
            const float* ap = &Aa[(size_t)koff * RR + rcol];
            bf16x8 bf;
            bf[0] = (__bf16)ap[0 * RR]; bf[1] = (__bf16)ap[1 * RR];
            bf[2] = (__bf16)ap[2 * RR]; bf[3] = (__bf16)ap[3 * RR];
            bf[4] = (__bf16)ap[4 * RR]; bf[5] = (__bf16)ap[5 * RR];
            bf[6] = (__bf16)ap[6 * RR]; bf[7] = (__bf16)ap[7 * RR];
            acc0 = __builtin_amdgcn_mfma_f32_16x16x32_bf16(af0, bf, acc0, 0, 0, 0);
            acc1 = __builtin_amdgcn_mfma_f32_16x16x32_bf16(af1, bf, acc1, 0, 0, 0);
        }
    }
    #pragma unroll
    for (int q = 0; q < 4; ++q) {
        inter[(size_t)(m0 + kg * 4 + q) * RR + rcol]      = (__bf16)acc0[q];
        inter[(size_t)(m0 + 16 + kg * 4 + q) * RR + rcol] = (__bf16)acc1[q];
    }
}

__global__ __launch_bounds__(256) void k_by_fb(
    const __bf16* __restrict__ inter, const float* __restrict__ base,
    const int* __restrict__ idx, const float* __restrict__ Bw,
    const float* __restrict__ scal, float* __restrict__ out)
{
    const int o0 = blockIdx.x * 64;
    const int m0 = blockIdx.y * 64;
    const int a  = idx[m0 / TSEQ];
    const float s = scal[a];
    const float* __restrict__ Ba = Bw + (size_t)a * RR * DOUT;
    const int lane = threadIdx.x & 63;
    const int w    = threadIdx.x >> 6;
    const int mr   = lane & 15, kg = lane >> 4;
    const int oc   = o0 + w * 16 + mr;

    f32x4 z = {0.f, 0.f, 0.f, 0.f};
    f32x4 acc[4] = {z, z, z, z};

    #pragma unroll
    for (int ksub = 0; ksub < 2; ++ksub) {
        const int kb = ksub * 32 + kg * 8;
        const float* bp = &Ba[(size_t)kb * DOUT + oc];
        bf16x8 bf;
        bf[0] = (__bf16)bp[0 * DOUT]; bf[1] = (__bf16)bp[1 * DOUT];
        bf[2] = (__bf16)bp[2 * DOUT]; bf[3] = (__bf16)bp[3 * DOUT];
        bf[4] = (__bf16)bp[4 * DOUT]; bf[5] = (__bf16)bp[5 * DOUT];
        bf[6] = (__bf16)bp[6 * DOUT]; bf[7] = (__bf16)bp[7 * DOUT];
        #pragma unroll
        for (int mt = 0; mt < 4; ++mt) {
            bf16x8 af = *(const bf16x8*)&inter[(size_t)(m0 + mt * 16 + mr) * RR + kb];
            acc[mt] = __builtin_amdgcn_mfma_f32_16x16x32_bf16(af, bf, acc[mt], 0, 0, 0);
        }
    }
    #pragma unroll
    for (int mt = 0; mt < 4; ++mt) {
        #pragma unroll
        for (int q = 0; q < 4; ++q) {
            size_t off = (size_t)(m0 + mt * 16 + kg * 4 + q) * DOUT + oc;
            out[off] = base[off] + s * acc[mt][q];
        }
    }
}

// ---------------------------------------------------------------------------
extern "C" void kernel_launch(void* const* d_in, const int* in_sizes, int n_in,
                              void* d_out, int out_size, void* d_ws, size_t ws_size,
                              hipStream_t stream)
{
    const float* x    = (const float*)d_in[0];
    const float* base = (const float*)d_in[1];
    const int*   idx  = (const int*)  d_in[2];
    const float* A    = (const float*)d_in[3];
    const float* Bw   = (const float*)d_in[4];
    const float* scal = (const float*)d_in[5];
    float* out = (float*)d_out;

    const size_t INTER_B = (size_t)BT * RR * 2;              // 2 MB
    const size_t AT_B    = (size_t)NADP * RR * DIN * 2;      // 4 MB
    const size_t BT_B    = (size_t)NADP * DOUT * RR * 2;     // 4 MB

    if (ws_size >= INTER_B + AT_B + BT_B) {
        __bf16* inter2 = (__bf16*)d_ws;
        __bf16* At2    = (__bf16*)((char*)d_ws + INTER_B);
        __bf16* Bp     = (__bf16*)((char*)d_ws + INTER_B + AT_B);
        k_prep_a<<<dim3(1024), 256, 0, stream>>>(A, At2);
        k_prep_b<<<dim3(1024), 256, 0, stream>>>(Bw, Bp);
        k_xa<<<dim3(BT / 16),            256, 0, stream>>>(x, idx, At2, inter2);
        k_by<<<dim3(DOUT / 64, BT / 64), 256, 0, stream>>>(inter2, base, idx, Bp, scal, out);
    } else {
        __bf16* inter = (__bf16*)d_ws;
        k_xa_fb<<<dim3(BT / 32),            256, 0, stream>>>(x, idx, A, inter);
        k_by_fb<<<dim3(DOUT / 64, BT / 64), 256, 0, stream>>>(inter, base, idx, Bw, scal, out);
    }
}

// Round 11
// 205.012 us; speedup vs baseline: 1.4087x; 1.4087x over previous
//
#include <hip/hip_runtime.h>
#include <hip/hip_bf16.h>
#include <cstdint>
#include <cstddef>

#define BT    16384   // B*T
#define DIN   4096
#define DOUT  4096
#define RR    64
#define TSEQ  2048
#define NADP  8

typedef float  f32x4  __attribute__((ext_vector_type(4)));
typedef __bf16 bf16x8 __attribute__((ext_vector_type(8)));

static __device__ __forceinline__ unsigned short bf16_bits(float f) {
    return __builtin_bit_cast(unsigned short, (__bf16)f);
}

// inter2 swizzled layout: [mblk(1024)][rb(8)][mrow(16)][j(8)]
static __device__ __forceinline__ size_t i2_idx(int mblk, int rb, int mrow, int j) {
    return ((((size_t)mblk * 8 + rb) * 16 + mrow) * 8 + j);
}

// ---------------------------------------------------------------------------
// k_prep_a: At2[a][kq][r][j] = bf16(A[a][kq*8+j][r]).  (R8/R10 verbatim)
// ---------------------------------------------------------------------------
__global__ __launch_bounds__(256) void k_prep_a(
    const float* __restrict__ A, __bf16* __restrict__ At2)
{
    const int gtid = blockIdx.x * 256 + threadIdx.x;
    const int r  = gtid & 63;
    const int kb = (gtid >> 6) & (DIN / 8 - 1);
    const int a  = gtid >> 15;
    const float* __restrict__ src = A + (size_t)a * DIN * RR + (size_t)kb * 8 * RR + r;
    unsigned int u[4];
    #pragma unroll
    for (int p = 0; p < 4; ++p) {
        unsigned int lo = bf16_bits(src[(2 * p + 0) * RR]);
        unsigned int hi = bf16_bits(src[(2 * p + 1) * RR]);
        u[p] = lo | (hi << 16);
    }
    *(uint4*)&At2[(size_t)gtid * 8] = make_uint4(u[0], u[1], u[2], u[3]);
}

// ---------------------------------------------------------------------------
// k_prep_b: Bp[a][rb][o][j] = bf16(B[a][rb*8+j][o]).  (R8/R10 verbatim)
// ---------------------------------------------------------------------------
__global__ __launch_bounds__(256) void k_prep_b(
    const float* __restrict__ Bw, __bf16* __restrict__ Bp)
{
    const int gtid = blockIdx.x * 256 + threadIdx.x;
    const int o  = gtid & (DOUT - 1);
    const int rb = (gtid >> 12) & 7;
    const int a  = gtid >> 15;
    const float* __restrict__ src = Bw + (size_t)a * RR * DOUT + (size_t)rb * 8 * DOUT + o;
    unsigned int u[4];
    #pragma unroll
    for (int p = 0; p < 4; ++p) {
        unsigned int lo = bf16_bits(src[(2 * p + 0) * DOUT]);
        unsigned int hi = bf16_bits(src[(2 * p + 1) * DOUT]);
        u[p] = lo | (hi << 16);
    }
    *(uint4*)&Bp[(size_t)gtid * 8] = make_uint4(u[0], u[1], u[2], u[3]);
}

// ---------------------------------------------------------------------------
// k_xa: inter2 <- bf16( x @ A[a] ).
// grid BT/64 = 256 blocks, 4 waves; wave w = m-subtile [m0+w*16,+16) x 64r
// (R7 geometry: each wave streams DIFFERENT x rows). 4 MFMA chains share
// one x fragment. Depth-4 BRANCH-FREE register pipeline: #pragma unroll 4
// makes slot ks&3 compile-time; 124 main steps prefetch ks+4 unconditionally;
// 4-step compute-only tail. ~16 loads in flight per wave.
// ---------------------------------------------------------------------------
__global__ __launch_bounds__(256, 1) void k_xa(
    const float* __restrict__ x, const int* __restrict__ idx,
    const __bf16* __restrict__ At2, __bf16* __restrict__ inter2)
{
    const int m0   = blockIdx.x * 64;
    const int a    = idx[m0 / TSEQ];
    const int w    = threadIdx.x >> 6, lane = threadIdx.x & 63;
    const int mr   = lane & 15, kg = lane >> 4;
    const float*  __restrict__ xrow = x + (size_t)(m0 + w * 16 + mr) * DIN + kg * 8;
    // At2 frag (ks, n): element offset (ks*256 + n*16)*8 from this base:
    const __bf16* __restrict__ Aw = At2 + (size_t)a * RR * DIN + (size_t)(kg * 64 + mr) * 8;

    f32x4 z = {0.f, 0.f, 0.f, 0.f};
    f32x4 acc[4] = {z, z, z, z};

    f32x4  sx0[4], sx1[4];
    bf16x8 sa[4][4];

    // prologue: fill slots 0..3 (steps 0..3)
    #pragma unroll
    for (int s = 0; s < 4; ++s) {
        sx0[s] = *(const f32x4*)(xrow + s * 32);
        sx1[s] = *(const f32x4*)(xrow + s * 32 + 4);
        #pragma unroll
        for (int n = 0; n < 4; ++n)
            sa[s][n] = *(const bf16x8*)(Aw + ((size_t)s * 256 + n * 16) * 8);
    }

    #pragma unroll 4
    for (int ks = 0; ks < 124; ++ks) {
        const int s = ks & 3;                     // compile-time after unroll
        f32x4 u0 = sx0[s], u1 = sx1[s];           // copy out before overwrite
        bf16x8 a0 = sa[s][0], a1 = sa[s][1], a2 = sa[s][2], a3 = sa[s][3];
        // prefetch step ks+4 into slot s (unconditional: ks+4 <= 127)
        sx0[s] = *(const f32x4*)(xrow + (ks + 4) * 32);
        sx1[s] = *(const f32x4*)(xrow + (ks + 4) * 32 + 4);
        #pragma unroll
        for (int n = 0; n < 4; ++n)
            sa[s][n] = *(const bf16x8*)(Aw + ((size_t)(ks + 4) * 256 + n * 16) * 8);
        // compute step ks
        bf16x8 af;
        af[0] = (__bf16)u0[0]; af[1] = (__bf16)u0[1];
        af[2] = (__bf16)u0[2]; af[3] = (__bf16)u0[3];
        af[4] = (__bf16)u1[0]; af[5] = (__bf16)u1[1];
        af[6] = (__bf16)u1[2]; af[7] = (__bf16)u1[3];
        acc[0] = __builtin_amdgcn_mfma_f32_16x16x32_bf16(af, a0, acc[0], 0, 0, 0);
        acc[1] = __builtin_amdgcn_mfma_f32_16x16x32_bf16(af, a1, acc[1], 0, 0, 0);
        acc[2] = __builtin_amdgcn_mfma_f32_16x16x32_bf16(af, a2, acc[2], 0, 0, 0);
        acc[3] = __builtin_amdgcn_mfma_f32_16x16x32_bf16(af, a3, acc[3], 0, 0, 0);
    }

    // tail: steps 124..127, compute-only, fully unrolled (static slots)
    #pragma unroll
    for (int ks = 124; ks < 128; ++ks) {
        const int s = ks & 3;
        f32x4 u0 = sx0[s], u1 = sx1[s];
        bf16x8 af;
        af[0] = (__bf16)u0[0]; af[1] = (__bf16)u0[1];
        af[2] = (__bf16)u0[2]; af[3] = (__bf16)u0[3];
        af[4] = (__bf16)u1[0]; af[5] = (__bf16)u1[1];
        af[6] = (__bf16)u1[2]; af[7] = (__bf16)u1[3];
        #pragma unroll
        for (int n = 0; n < 4; ++n)
            acc[n] = __builtin_amdgcn_mfma_f32_16x16x32_bf16(af, sa[s][n], acc[n], 0, 0, 0);
    }

    // D layout: row = kg*4+q (m within wave tile), col = n*16+mr (r)
    const int mblk = blockIdx.x * 4 + w;
    #pragma unroll
    for (int n = 0; n < 4; ++n) {
        const int rb = n * 2 + (mr >> 3), j = mr & 7;
        #pragma unroll
        for (int q = 0; q < 4; ++q)
            inter2[i2_idx(mblk, rb, kg * 4 + q, j)] = (__bf16)acc[n][q];
    }
}

// ---------------------------------------------------------------------------
// k_by: out = base + s * (inter @ B).  (R8/R9/R10 verbatim, ~6.5 TB/s)
// ---------------------------------------------------------------------------
__global__ __launch_bounds__(256) void k_by(
    const __bf16* __restrict__ inter2, const float* __restrict__ base,
    const int* __restrict__ idx, const __bf16* __restrict__ Bp,
    const float* __restrict__ scal, float* __restrict__ out)
{
    const int o0 = blockIdx.x * 64;
    const int m0 = blockIdx.y * 64;
    const int a  = idx[m0 / TSEQ];
    const float s = scal[a];
    const __bf16* __restrict__ Ba = Bp + (size_t)a * RR * DOUT;
    const int lane = threadIdx.x & 63;
    const int w    = threadIdx.x >> 6;
    const int mr   = lane & 15, kg = lane >> 4;
    const int oc   = o0 + w * 16 + mr;

    f32x4 z = {0.f, 0.f, 0.f, 0.f};
    f32x4 acc[4] = {z, z, z, z};

    #pragma unroll
    for (int ksub = 0; ksub < 2; ++ksub) {
        const int rb = ksub * 4 + kg;
        bf16x8 bfA = *(const bf16x8*)&Ba[((size_t)rb * DOUT + oc) * 8];
        #pragma unroll
        for (int mt = 0; mt < 4; ++mt) {
            bf16x8 afB = *(const bf16x8*)&inter2[i2_idx(m0 / 16 + mt, rb, mr, 0)];
            acc[mt] = __builtin_amdgcn_mfma_f32_16x16x32_bf16(bfA, afB, acc[mt], 0, 0, 0);
        }
    }

    #pragma unroll
    for (int mt = 0; mt < 4; ++mt) {
        size_t off = (size_t)(m0 + mt * 16 + mr) * DOUT + o0 + w * 16 + kg * 4;
        float4 bv = *(const float4*)&base[off];
        float4 o;
        o.x = bv.x + s * acc[mt][0];
        o.y = bv.y + s * acc[mt][1];
        o.z = bv.z + s * acc[mt][2];
        o.w = bv.w + s * acc[mt][3];
        *(float4*)&out[off] = o;
    }
}

// ---------------------------------------------------------------------------
// Fallback kernels (R6 verbatim, 2 MB ws) if ws_size < 10 MB.
// ---------------------------------------------------------------------------
__global__ __launch_bounds__(256) void k_xa_fb(
    const float* __restrict__ x, const int* __restrict__ idx,
    const float* __restrict__ A, __bf16* __restrict__ inter)
{
    const int m0   = blockIdx.x * 32;
    const int a    = idx[m0 / TSEQ];
    const float* __restrict__ Aa = A + (size_t)a * DIN * RR;
    const int lane = threadIdx.x & 63;
    const int rw   = threadIdx.x >> 6;
    const int mr   = lane & 15, kg = lane >> 4;
    const int rcol = rw * 16 + mr;
    const float* __restrict__ xrow0 = x + (size_t)(m0 + mr) * DIN;
    const float* __restrict__ xrow1 = x + (size_t)(m0 + 16 + mr) * DIN;

    f32x4 acc0 = {0.f, 0.f, 0.f, 0.f};
    f32x4 acc1 = {0.f, 0.f, 0.f, 0.f};

    for (int k0 = 0; k0 < DIN; k0 += 64) {
        #pragma unroll
        for (int ksub = 0; ksub < 2; ++ksub) {
            const int koff = k0 + ksub * 32 + kg * 8;
            float4 u0 = *(const float4*)&xrow0[koff];
            float4 u1 = *(const float4*)&xrow0[koff + 4];
            float4 v0 = *(const float4*)&xrow1[koff];
            float4 v1 = *(const float4*)&xrow1[koff + 4];
            bf16x8 af0, af1;
            af0[0] = (__bf16)u0.x; af0[1] = (__bf16)u0.y;
            af0[2] = (__bf16)u0.z; af0[3] = (__bf16)u0.w;
            af0[4] = (__bf16)u1.x; af0[5] = (__bf16)u1.y;
            af0[6] = (__bf16)u1.z; af0[7] = (__bf16)u1.w;
            af1[0] = (__bf16)v0.x; af1[1] = (__bf16)v0.y;
            af1[2] = (__bf16)v0.z; af1[3] = (__bf16)v0.w;
            af1[4] = (__bf16)v1.x; af1[5] = (__bf16)v1.y;
            af1[6] = (__bf16)v1.z; af1[7] = (__bf16)v1.w;
            const float* ap = &Aa[(size_t)koff * RR + rcol];
            bf16x8 bf;
            bf[0] = (__bf16)ap[0 * RR]; bf[1] = (__bf16)ap[1 * RR];
            bf[2] = (__bf16)ap[2 * RR]; bf[3] = (__bf16)ap[3 * RR];
            bf[4] = (__bf16)ap[4 * RR]; bf[5] = (__bf16)ap[5 * RR];
            bf[6] = (__bf16)ap[6 * RR]; bf[7] = (__bf16)ap[7 * RR];
            acc0 = __builtin_amdgcn_mfma_f32_16x16x32_bf16(af0, bf, acc0, 0, 0, 0);
            acc1 = __builtin_amdgcn_mfma_f32_16x16x32_bf16(af1, bf, acc1, 0, 0, 0);
        }
    }
    #pragma unroll
    for (int q = 0; q < 4; ++q) {
        inter[(size_t)(m0 + kg * 4 + q) * RR + rcol]      = (__bf16)acc0[q];
        inter[(size_t)(m0 + 16 + kg * 4 + q) * RR + rcol] = (__bf16)acc1[q];
    }
}

__global__ __launch_bounds__(256) void k_by_fb(
    const __bf16* __restrict__ inter, const float* __restrict__ base,
    const int* __restrict__ idx, const float* __restrict__ Bw,
    const float* __restrict__ scal, float* __restrict__ out)
{
    const int o0 = blockIdx.x * 64;
    const int m0 = blockIdx.y * 64;
    const int a  = idx[m0 / TSEQ];
    const float s = scal[a];
    const float* __restrict__ Ba = Bw + (size_t)a * RR * DOUT;
    const int lane = threadIdx.x & 63;
    const int w    = threadIdx.x >> 6;
    const int mr   = lane & 15, kg = lane >> 4;
    const int oc   = o0 + w * 16 + mr;

    f32x4 z = {0.f, 0.f, 0.f, 0.f};
    f32x4 acc[4] = {z, z, z, z};

    #pragma unroll
    for (int ksub = 0; ksub < 2; ++ksub) {
        const int kb = ksub * 32 + kg * 8;
        const float* bp = &Ba[(size_t)kb * DOUT + oc];
        bf16x8 bf;
        bf[0] = (__bf16)bp[0 * DOUT]; bf[1] = (__bf16)bp[1 * DOUT];
        bf[2] = (__bf16)bp[2 * DOUT]; bf[3] = (__bf16)bp[3 * DOUT];
        bf[4] = (__bf16)bp[4 * DOUT]; bf[5] = (__bf16)bp[5 * DOUT];
        bf[6] = (__bf16)bp[6 * DOUT]; bf[7] = (__bf16)bp[7 * DOUT];
        #pragma unroll
        for (int mt = 0; mt < 4; ++mt) {
            bf16x8 af = *(const bf16x8*)&inter[(size_t)(m0 + mt * 16 + mr) * RR + kb];
            acc[mt] = __builtin_amdgcn_mfma_f32_16x16x32_bf16(af, bf, acc[mt], 0, 0, 0);
        }
    }
    #pragma unroll
    for (int mt = 0; mt < 4; ++mt) {
        #pragma unroll
        for (int q = 0; q < 4; ++q) {
            size_t off = (size_t)(m0 + mt * 16 + kg * 4 + q) * DOUT + oc;
            out[off] = base[off] + s * acc[mt][q];
        }
    }
}

// ---------------------------------------------------------------------------
extern "C" void kernel_launch(void* const* d_in, const int* in_sizes, int n_in,
                              void* d_out, int out_size, void* d_ws, size_t ws_size,
                              hipStream_t stream)
{
    const float* x    = (const float*)d_in[0];
    const float* base = (const float*)d_in[1];
    const int*   idx  = (const int*)  d_in[2];
    const float* A    = (const float*)d_in[3];
    const float* Bw   = (const float*)d_in[4];
    const float* scal = (const float*)d_in[5];
    float* out = (float*)d_out;

    const size_t INTER_B = (size_t)BT * RR * 2;              // 2 MB
    const size_t AT_B    = (size_t)NADP * RR * DIN * 2;      // 4 MB
    const size_t BT_B    = (size_t)NADP * DOUT * RR * 2;     // 4 MB

    if (ws_size >= INTER_B + AT_B + BT_B) {
        __bf16* inter2 = (__bf16*)d_ws;
        __bf16* At2    = (__bf16*)((char*)d_ws + INTER_B);
        __bf16* Bp     = (__bf16*)((char*)d_ws + INTER_B + AT_B);
        k_prep_a<<<dim3(1024), 256, 0, stream>>>(A, At2);
        k_prep_b<<<dim3(1024), 256, 0, stream>>>(Bw, Bp);
        k_xa<<<dim3(BT / 64),            256, 0, stream>>>(x, idx, At2, inter2);
        k_by<<<dim3(DOUT / 64, BT / 64), 256, 0, stream>>>(inter2, base, idx, Bp, scal, out);
    } else {
        __bf16* inter = (__bf16*)d_ws;
        k_xa_fb<<<dim3(BT / 32),            256, 0, stream>>>(x, idx, A, inter);
        k_by_fb<<<dim3(DOUT / 64, BT / 64), 256, 0, stream>>>(inter, base, idx, Bw, scal, out);
    }
}